// Round 2
// baseline (2916.478 us; speedup 1.0000x reference)
//
#include <hip/hip_runtime.h>
#include <stdint.h>

// ---------------------------------------------------------------------------
// Critic: encoder -> 255-step LSTM (U=256, D_in=256) -> 1-unit relu head. B=512
//
// Round-5 design (fix: rounds 3/4 overcommitted the register file, forcing
// scratch spills of Wrk tiles whose reloads serialized the MFMA path):
//  - Per consumer wave (8 tiles of Wrk): 3 tiles in VGPRs (96), 2 in LDS,
//    3 STREAMED from L2 every step through one recycled 32-VGPR buffer
//    (t3 -> t6 -> t7, disjoint lifetimes, each issued ~>=200cy before use).
//    Declared register need ~230 < 256 cap at 2 waves/SIMD -> no spill.
//  - A-fragments (h row) read once per step into a8[8] and reused by all
//    8 tile loops -> 24 b128 LDS reads/wave/step, under the MFMA shadow.
//  - f32 z-ring with direct accumulator loads + cross-step accA prefetch,
//    window-granular agent handshake, producers: unchanged from round 4.
// ---------------------------------------------------------------------------

#define NSTEP 255

typedef __attribute__((ext_vector_type(8))) short short8;   // 8 x bf16
typedef __attribute__((ext_vector_type(4))) float f32x4;

__device__ __forceinline__ unsigned short f2bf(float f) {
    union { float f; unsigned int u; } v; v.f = f;
    unsigned int r = v.u + 0x7FFFu + ((v.u >> 16) & 1u);   // RNE
    return (unsigned short)(r >> 16);
}
__device__ __forceinline__ float fexp2(float x) { return __builtin_amdgcn_exp2f(x); }
__device__ __forceinline__ float frcp(float x)  { return __builtin_amdgcn_rcpf(x); }
__device__ __forceinline__ float sigm(float x)  { return frcp(1.0f + fexp2(-1.44269504f * x)); }
__device__ __forceinline__ float tanh_(float x) { return 1.0f - 2.0f * frcp(1.0f + fexp2(2.88539008f * x)); }

// ---------------------------------------------------------------------------
// Encoder: state = relu(concat(ms,rs,re,im) @ Wc + bc)   [512,256] fp32
// ---------------------------------------------------------------------------
__global__ __launch_bounds__(256)
void encoder_kernel(const float* __restrict__ motion, const float* __restrict__ robot,
                    const float* __restrict__ osr, const float* __restrict__ osi,
                    const float* __restrict__ ore, const float* __restrict__ oie,
                    const float* __restrict__ Wm, const float* __restrict__ bm,
                    const float* __restrict__ Wr, const float* __restrict__ br,
                    const float* __restrict__ Wre, const float* __restrict__ bre,
                    const float* __restrict__ Wim, const float* __restrict__ bim,
                    const float* __restrict__ Wc, const float* __restrict__ bc,
                    float* __restrict__ state)
{
    __shared__ float in_m[16][64];
    __shared__ float in_r[16][128];
    __shared__ float in_re[16][128];
    __shared__ float in_im[16][128];
    __shared__ float catb[16 * 768];
    const int t = threadIdx.x;
    const int m0 = blockIdx.x * 16;

    {
        int idx = t * 4; int row = idx >> 6, col = idx & 63;
        *(float4*)&in_m[row][col]       = *(const float4*)(motion + (m0 + row) * 64 + col);
        *(float4*)&in_re[row][col]      = *(const float4*)(osr + (m0 + row) * 64 + col);
        *(float4*)&in_re[row][64 + col] = *(const float4*)(ore + (m0 + row) * 64 + col);
        *(float4*)&in_im[row][col]      = *(const float4*)(osi + (m0 + row) * 64 + col);
        *(float4*)&in_im[row][64 + col] = *(const float4*)(oie + (m0 + row) * 64 + col);
    }
    for (int p = 0; p < 2; ++p) {
        int idx = (t + p * 256) * 4; int row = idx >> 7, col = idx & 127;
        *(float4*)&in_r[row][col] = *(const float4*)(robot + (m0 + row) * 128 + col);
    }
    __syncthreads();

    for (int row = 0; row < 16; ++row) {
        {
            float s = bm[t];
            for (int k = 0; k < 64; ++k) s += in_m[row][k] * Wm[k * 256 + t];
            catb[row * 768 + t] = fmaxf(s, 0.0f);
        }
        {
            float s = br[t];
            for (int k = 0; k < 128; ++k) s += in_r[row][k] * Wr[k * 256 + t];
            catb[row * 768 + 256 + t] = fmaxf(s, 0.0f);
        }
        if (t < 128) {
            float s = bre[t];
            for (int k = 0; k < 128; ++k) s += in_re[row][k] * Wre[k * 128 + t];
            catb[row * 768 + 512 + t] = fmaxf(s, 0.0f);
        } else {
            const int u = t - 128;
            float s = bim[u];
            for (int k = 0; k < 128; ++k) s += in_im[row][k] * Wim[k * 128 + u];
            catb[row * 768 + 640 + u] = fmaxf(s, 0.0f);
        }
    }
    __syncthreads();

    for (int r0 = 0; r0 < 16; r0 += 4) {
        float a0 = bc[t], a1 = bc[t], a2 = bc[t], a3 = bc[t];
        for (int j = 0; j < 768; ++j) {
            const float wv = Wc[j * 256 + t];
            a0 += catb[(r0 + 0) * 768 + j] * wv;
            a1 += catb[(r0 + 1) * 768 + j] * wv;
            a2 += catb[(r0 + 2) * 768 + j] * wv;
            a3 += catb[(r0 + 3) * 768 + j] * wv;
        }
        state[(m0 + r0 + 0) * 256 + t] = fmaxf(a0, 0.0f);
        state[(m0 + r0 + 1) * 256 + t] = fmaxf(a1, 0.0f);
        state[(m0 + r0 + 2) * 256 + t] = fmaxf(a2, 0.0f);
        state[(m0 + r0 + 3) * 256 + t] = fmaxf(a3, 0.0f);
    }
}

// ---------------------------------------------------------------------------
// Prep: W2k/W2r in frag-linear layout [(T*8+kk)*64+lane][8], bf16.
//   Tile T = wv4*16 + gam*4 + g  -> orig col = g*256 + wv4*64 + gam*16 + cid
//   frag element j: k = kk*32 + (lane>>4)*8 + j  (B layout: n=lane&15).
// blr2[T*64+lane] = bl[orig col].  Also zero flags.
// ---------------------------------------------------------------------------
__global__ __launch_bounds__(256)
void prep_kernel(const float* __restrict__ Wk, const float* __restrict__ Wrk,
                 const float* __restrict__ bl,
                 unsigned short* __restrict__ W2k, unsigned short* __restrict__ W2r,
                 float* __restrict__ blr2,
                 unsigned int* __restrict__ prod_flag, unsigned int* __restrict__ cons_prog)
{
    const int blk = blockIdx.x, t = threadIdx.x;
    if (blk < 256) {
        const int mat = blk >> 7;
        const int idx = (blk & 127) * 256 + t;      // (T*8+kk)*64+lane
        const int T = idx >> 9, kk = (idx >> 6) & 7, lane = idx & 63;
        const int q = lane >> 4, cid = lane & 15;
        const int wv = T >> 4, gam = (T >> 2) & 3, g = T & 3;
        const int col = g * 256 + wv * 64 + gam * 16 + cid;
        const float* W = mat ? Wrk : Wk;
        unsigned short* O = mat ? W2r : W2k;
#pragma unroll
        for (int j = 0; j < 8; ++j) {
            const int k = kk * 32 + q * 8 + j;
            O[(size_t)idx * 8 + j] = f2bf(W[(size_t)k * 1024 + col]);
        }
    } else {
        for (int e = t; e < 4096; e += 256) {
            const int T = e >> 6, lane = e & 63, cid = lane & 15;
            const int wv = T >> 4, gam = (T >> 2) & 3, g = T & 3;
            blr2[e] = bl[g * 256 + wv * 64 + gam * 16 + cid];
        }
        for (int i = t; i < 40960; i += 256) prod_flag[i] = 0u;
        for (int i = t; i < 512; i += 256) cons_prog[i] = 0u;
    }
}

// ---------------------------------------------------------------------------
// Fused: blocks 0..31 = consumers (recurrence, 8 waves), 32..255 = producers.
// z ring is f32 C-fragments: z[(slot*32+m)*16384 + (T*64+lane)*4 .. +3]
// ---------------------------------------------------------------------------
__global__ __launch_bounds__(512, 2)
void fused_kernel(const float* __restrict__ hist, const float* __restrict__ act,
                  const float* __restrict__ state,
                  const unsigned short* __restrict__ W2k, const unsigned short* __restrict__ W2r,
                  const float* __restrict__ blr2,
                  const float* __restrict__ Wo, const float* __restrict__ bo_p,
                  float* __restrict__ zf32, float* __restrict__ hfing,
                  unsigned int* __restrict__ prod_flag, unsigned int* __restrict__ cons_prog,
                  float* __restrict__ out,
                  int WSH, int NW, int RS, int ring_steps)
{
    __shared__ __align__(16) unsigned char smem[147968];
    unsigned short* ldsW = (unsigned short*)smem;                 // 131072 B (2 Wrk tiles / wave)
    unsigned short* hbuf0 = (unsigned short*)(smem + 131072);     // 8448 B
    unsigned short* hbuf1 = (unsigned short*)(smem + 139520);     // 8448 B

    const int tid = threadIdx.x;
    const int w = tid >> 6, lane = tid & 63, q = lane >> 4, cid = lane & 15;
    const int bx = blockIdx.x;
    const int WIN = 1 << WSH, WMASK = WIN - 1;

    if (bx < 32) {
        // ======================= CONSUMER =======================
        const int m = bx, m0 = m * 16;
        // wave w owns tiles T = w*8 + j; gate = j&3 (i,f,g,o), half = j>>2
        // units: u(h) = (w>>1)*64 + ((w&1)*2 + h)*16 + cid
        const int u0 = (w >> 1) * 64 + ((w & 1) * 2 + 0) * 16 + cid;
        const int u1 = u0 + 16;

        // register-resident Wrk: tiles j=0,1,2 (96 VGPR)
        short8 Wres[3][8];
#pragma unroll
        for (int t = 0; t < 3; ++t) {
#pragma unroll
            for (int kk = 0; kk < 8; ++kk)
                Wres[t][kk] = *(const short8*)(W2r + ((size_t)((w * 8 + t) * 8 + kk) * 64 + lane) * 8);
        }
        // LDS-resident Wrk: tiles j=4,5
#pragma unroll
        for (int tt = 0; tt < 2; ++tt) {
#pragma unroll
            for (int kk = 0; kk < 8; ++kk) {
                short8 f = *(const short8*)(W2r + ((size_t)((w * 8 + 4 + tt) * 8 + kk) * 64 + lane) * 8);
                *(short8*)(ldsW + (((w * 2 + tt) * 8 + kk) * 64 + lane) * 8) = f;
            }
        }
        // streamed-tile base (shorts): tile T starts at T*4096
        const unsigned short* swB = W2r + (size_t)(w * 8) * 4096 + (size_t)lane * 8;
        // h^0 = bf16(state tile): 512 threads x 8 elems
        {
            const int row = tid >> 5, c0 = (tid & 31) * 8;
            const float* sp = state + (size_t)(m0 + row) * 256 + c0;
            const float4 a = *(const float4*)sp;
            const float4 b = *(const float4*)(sp + 4);
            union { unsigned short us[8]; short8 v; } pk;
            pk.us[0] = f2bf(a.x); pk.us[1] = f2bf(a.y); pk.us[2] = f2bf(a.z); pk.us[3] = f2bf(a.w);
            pk.us[4] = f2bf(b.x); pk.us[5] = f2bf(b.y); pk.us[6] = f2bf(b.z); pk.us[7] = f2bf(b.w);
            *(short8*)(hbuf0 + row * 264 + c0) = pk.v;
        }
        // c^0
        float cc[8];
#pragma unroll
        for (int h = 0; h < 2; ++h)
#pragma unroll
            for (int r = 0; r < 4; ++r)
                cc[h * 4 + r] = state[(size_t)(m0 + q * 4 + r) * 256 + (h ? u1 : u0)];

        __syncthreads();

        unsigned short* hcur = hbuf0;
        unsigned short* hnxt = hbuf1;
        int zslot = 0;
        f32x4 accA[4], accB[4];
        const float* zbw = zf32 + (size_t)lane * 4 + (size_t)w * 2048;  // + w*8*256

        for (int s = 0; s < NSTEP; ++s) {
            const bool last = (s == NSTEP - 1);

            // stream tile j=3 (gate o, u0) -- issue before any waiting
            short8 strm[8];
#pragma unroll
            for (int kk = 0; kk < 8; ++kk)
                strm[kk] = *(const short8*)(swB + (size_t)3 * 4096 + kk * 512);

            if ((s & WMASK) == 0) {
                const int f = s >> WSH;
                while (__hip_atomic_load(&prod_flag[(f * 32 + m) * 4],
                                         __ATOMIC_ACQUIRE, __HIP_MEMORY_SCOPE_AGENT) == 0)
                    __builtin_amdgcn_s_sleep(1);
                const float* zb0 = zbw + ((size_t)zslot * 32 + m) * 16384;
#pragma unroll
                for (int g = 0; g < 4; ++g)
                    accA[g] = *(const f32x4*)(zb0 + g * 256);
            }
            {
                const float* zb1 = zbw + ((size_t)zslot * 32 + m) * 16384 + 1024;
#pragma unroll
                for (int g = 0; g < 4; ++g)
                    accB[g] = *(const f32x4*)(zb1 + g * 256);
            }
            const unsigned short* hrow = hcur + cid * 264 + q * 8;

            // A-fragments once per step (reused by all 8 tile loops)
            short8 a8[8];

            // half 0 part A: register tiles 0..2 (i,f,g of u0)
            __builtin_amdgcn_s_setprio(1);
#pragma unroll
            for (int kk = 0; kk < 8; ++kk) {
                a8[kk] = *(const short8*)(hrow + kk * 32);
                accA[0] = __builtin_amdgcn_mfma_f32_16x16x32_bf16(a8[kk], Wres[0][kk], accA[0], 0, 0, 0);
                accA[1] = __builtin_amdgcn_mfma_f32_16x16x32_bf16(a8[kk], Wres[1][kk], accA[1], 0, 0, 0);
                accA[2] = __builtin_amdgcn_mfma_f32_16x16x32_bf16(a8[kk], Wres[2][kk], accA[2], 0, 0, 0);
            }
            // half 0 part B: streamed tile 3 (o of u0) -- loads covered by part A
#pragma unroll
            for (int kk = 0; kk < 8; ++kk)
                accA[3] = __builtin_amdgcn_mfma_f32_16x16x32_bf16(a8[kk], strm[kk], accA[3], 0, 0, 0);
            __builtin_amdgcn_s_setprio(0);

            // stream tile j=6 (g of u1) -- consumed after LDS tiles + gates
#pragma unroll
            for (int kk = 0; kk < 8; ++kk)
                strm[kk] = *(const short8*)(swB + (size_t)6 * 4096 + kk * 512);

#pragma unroll
            for (int r = 0; r < 4; ++r) {
                const float c = sigm(accA[1][r]) * cc[r] + sigm(accA[0][r]) * tanh_(accA[2][r]);
                cc[r] = c;
                const float hv = sigm(accA[3][r]) * tanh_(c);
                if (!last) hnxt[(q * 4 + r) * 264 + u0] = f2bf(hv);
                else       hfing[(size_t)(m0 + q * 4 + r) * 256 + u0] = hv;
            }

            // prefetch z(s+1) half-0 into accA while half-1 computes
            const int znext = (zslot + 1 == ring_steps) ? 0 : zslot + 1;
            if (!last && (((s + 1) & WMASK) != 0)) {
                const float* zbn = zbw + ((size_t)znext * 32 + m) * 16384;
#pragma unroll
                for (int g = 0; g < 4; ++g)
                    accA[g] = *(const f32x4*)(zbn + g * 256);
            }

            // half 1 part A: LDS tiles 4,5 (i,f of u1)
            __builtin_amdgcn_s_setprio(1);
#pragma unroll
            for (int kk = 0; kk < 8; ++kk) {
                const short8 b4 = *(const short8*)(ldsW + (((w * 2 + 0) * 8 + kk) * 64 + lane) * 8);
                accB[0] = __builtin_amdgcn_mfma_f32_16x16x32_bf16(a8[kk], b4, accB[0], 0, 0, 0);
                const short8 b5 = *(const short8*)(ldsW + (((w * 2 + 1) * 8 + kk) * 64 + lane) * 8);
                accB[1] = __builtin_amdgcn_mfma_f32_16x16x32_bf16(a8[kk], b5, accB[1], 0, 0, 0);
            }
            // half 1 part B: streamed tile 6
#pragma unroll
            for (int kk = 0; kk < 8; ++kk)
                accB[2] = __builtin_amdgcn_mfma_f32_16x16x32_bf16(a8[kk], strm[kk], accB[2], 0, 0, 0);
            __builtin_amdgcn_s_setprio(0);

            // stream tile j=7 (o of u1)
#pragma unroll
            for (int kk = 0; kk < 8; ++kk)
                strm[kk] = *(const short8*)(swB + (size_t)7 * 4096 + kk * 512);

            __builtin_amdgcn_s_setprio(1);
#pragma unroll
            for (int kk = 0; kk < 8; ++kk)
                accB[3] = __builtin_amdgcn_mfma_f32_16x16x32_bf16(a8[kk], strm[kk], accB[3], 0, 0, 0);
            __builtin_amdgcn_s_setprio(0);

#pragma unroll
            for (int r = 0; r < 4; ++r) {
                const float c = sigm(accB[1][r]) * cc[4 + r] + sigm(accB[0][r]) * tanh_(accB[2][r]);
                cc[4 + r] = c;
                const float hv = sigm(accB[3][r]) * tanh_(c);
                if (!last) hnxt[(q * 4 + r) * 264 + u1] = f2bf(hv);
                else       hfing[(size_t)(m0 + q * 4 + r) * 256 + u1] = hv;
            }

            __syncthreads();
            { unsigned short* t_ = hcur; hcur = hnxt; hnxt = t_; }
            if (((s + 1) & WMASK) == 0 && tid == 0)
                __hip_atomic_store(&cons_prog[m * 16], (unsigned)((s + 1) >> WSH),
                                   __ATOMIC_RELEASE, __HIP_MEMORY_SCOPE_AGENT);
            zslot = znext;
        }

        // head: out = relu(h_final @ Wo + bo)
        float* redL = (float*)smem;       // reuse ldsW region
        if (tid < 256) {
            const int row = tid >> 4, c16 = tid & 15;
            float part = 0.0f;
#pragma unroll
            for (int j = 0; j < 16; ++j) {
                const int u = c16 + j * 16;
                part += hfing[(size_t)(m0 + row) * 256 + u] * Wo[u];
            }
            redL[row * 16 + c16] = part;
        }
        __syncthreads();
        if (tid < 16) {
            float sum = 0.0f;
#pragma unroll
            for (int j = 0; j < 16; ++j) sum += redL[tid * 16 + j];
            out[m0 + tid] = fmaxf(sum + bo_p[0], 0.0f);
        }
    } else {
        // ======================= PRODUCER =======================
        const int p = bx - 32;
        const int total = NW * 32;
        const int slot0 = w & 3, tchalf = w >> 2;   // 4 step-slots x 2 Tc halves
        for (int tau = p; tau < total; tau += 224) {
            const int w_ = tau >> 5, m = tau & 31, m0 = m * 16;
            const int nst = (WIN < NSTEP - w_ * WIN) ? WIN : (NSTEP - w_ * WIN);
            if (w_ >= RS) {
                const unsigned need = (unsigned)(w_ - RS + 1);
                while (__hip_atomic_load(&cons_prog[m * 16],
                                         __ATOMIC_ACQUIRE, __HIP_MEMORY_SCOPE_AGENT) < need)
                    __builtin_amdgcn_s_sleep(4);
            }
            int ns_my = 0; int sabs[2] = {0, 0};
            for (int sl = slot0; sl < nst; sl += 4) { if (ns_my < 2) sabs[ns_my++] = w_ * WIN + sl; }

            short8 A2[2][8];
#pragma unroll
            for (int si = 0; si < 2; ++si) {
                if (si < ns_my) {
                    const int s = sabs[si];
                    const float* xs = (s < 127)
                        ? hist + ((size_t)(m0 + cid) * 128 + s) * 256
                        : act + ((size_t)(m0 + cid) * 128 + (s - 127)) * 256;
#pragma unroll
                    for (int kk = 0; kk < 8; ++kk) {
                        const float4 a = *(const float4*)(xs + kk * 32 + q * 8);
                        const float4 b = *(const float4*)(xs + kk * 32 + q * 8 + 4);
                        union { unsigned short us[8]; short8 v; } pk;
                        pk.us[0] = f2bf(a.x); pk.us[1] = f2bf(a.y);
                        pk.us[2] = f2bf(a.z); pk.us[3] = f2bf(a.w);
                        pk.us[4] = f2bf(b.x); pk.us[5] = f2bf(b.y);
                        pk.us[6] = f2bf(b.z); pk.us[7] = f2bf(b.w);
                        A2[si][kk] = pk.v;
                    }
                }
            }
            if (ns_my > 0) {
                for (int Tc = tchalf * 8; Tc < tchalf * 8 + 8; ++Tc) {
                    float bias[4];
#pragma unroll
                    for (int t = 0; t < 4; ++t) bias[t] = blr2[(Tc * 4 + t) * 64 + lane];
                    f32x4 acc[2][4];
#pragma unroll
                    for (int si = 0; si < 2; ++si)
#pragma unroll
                        for (int t = 0; t < 4; ++t)
                            acc[si][t] = (f32x4){bias[t], bias[t], bias[t], bias[t]};
#pragma unroll
                    for (int kk = 0; kk < 8; ++kk) {
                        short8 Wf[4];
#pragma unroll
                        for (int t = 0; t < 4; ++t)
                            Wf[t] = *(const short8*)(W2k + ((size_t)((Tc * 4 + t) * 8 + kk) * 64 + lane) * 8);
#pragma unroll
                        for (int t = 0; t < 4; ++t) {
                            acc[0][t] = __builtin_amdgcn_mfma_f32_16x16x32_bf16(A2[0][kk], Wf[t], acc[0][t], 0, 0, 0);
                            if (ns_my > 1)
                                acc[1][t] = __builtin_amdgcn_mfma_f32_16x16x32_bf16(A2[1][kk], Wf[t], acc[1][t], 0, 0, 0);
                        }
                    }
#pragma unroll
                    for (int si = 0; si < 2; ++si) {
                        if (si < ns_my) {
                            const int zsl = sabs[si] % ring_steps;
                            float* zo_ = zf32 + ((size_t)zsl * 32 + m) * 16384 + (size_t)lane * 4;
#pragma unroll
                            for (int t = 0; t < 4; ++t)
                                *(f32x4*)(zo_ + (Tc * 4 + t) * 256) = acc[si][t];
                        }
                    }
                }
            }
            __syncthreads();
            if (tid == 0)
                __hip_atomic_store(&prod_flag[(w_ * 32 + m) * 4], 1u,
                                   __ATOMIC_RELEASE, __HIP_MEMORY_SCOPE_AGENT);
        }
    }
}

// ---------------------------------------------------------------------------
extern "C" void kernel_launch(void* const* d_in, const int* in_sizes, int n_in,
                              void* d_out, int out_size, void* d_ws, size_t ws_size,
                              hipStream_t stream)
{
    const float* motion = (const float*)d_in[0];
    const float* robot  = (const float*)d_in[1];
    const float* osr    = (const float*)d_in[2];
    const float* osi    = (const float*)d_in[3];
    const float* hist   = (const float*)d_in[4];
    const float* act    = (const float*)d_in[5];
    const float* ore    = (const float*)d_in[6];
    const float* oie    = (const float*)d_in[7];
    const float* Wm  = (const float*)d_in[8];  const float* bm  = (const float*)d_in[9];
    const float* Wr  = (const float*)d_in[10]; const float* br  = (const float*)d_in[11];
    const float* Wre = (const float*)d_in[12]; const float* bre = (const float*)d_in[13];
    const float* Wim = (const float*)d_in[14]; const float* bim = (const float*)d_in[15];
    const float* Wc  = (const float*)d_in[16]; const float* bc  = (const float*)d_in[17];
    const float* Wk  = (const float*)d_in[18];
    const float* Wrk = (const float*)d_in[19];
    const float* bl  = (const float*)d_in[20];
    const float* Wo  = (const float*)d_in[21]; const float* bo  = (const float*)d_in[22];

    char* ws = (char*)d_ws;
    float*          state     = (float*)(ws + 0);                  // 524288
    unsigned short* W2k       = (unsigned short*)(ws + 524288);    // 524288
    unsigned short* W2r       = (unsigned short*)(ws + 1048576);   // 524288
    float*          blr2      = (float*)(ws + 1572864);            // 16384
    unsigned int*   prod_flag = (unsigned int*)(ws + 1589248);     // 163840
    unsigned int*   cons_prog = (unsigned int*)(ws + 1753088);     // 2048
    float*          hfing     = (float*)(ws + 1755136);            // 524288 final-h scratch
    float*          zf32      = (float*)(ws + 2279424);            // f32 ring
    float*          out       = (float*)d_out;

    // adaptive ring: per-step z is 2 MB (32 tiles x 64 KB f32)
    size_t avail = (ws_size > 2279424) ? ws_size - 2279424 : 0;
    long rs_max = (long)(avail / 2097152);
    int WIN = 1, NW = 255, RS = 1;
    const int wins[4] = {8, 4, 2, 1};
    for (int i = 0; i < 4; ++i) {
        const int Wn = wins[i];
        const int nw = (NSTEP + Wn - 1) / Wn;
        long rs = rs_max / Wn; if (rs > nw) rs = nw;
        if (rs >= 2) { WIN = Wn; NW = nw; RS = (int)rs; break; }
        if (Wn == 1) { WIN = 1; NW = nw; RS = (int)(rs >= 1 ? rs : 1); }
    }
    int ring_steps = RS * WIN; if (ring_steps < 1) ring_steps = 1;
    const int WSH = (WIN == 8) ? 3 : (WIN == 4) ? 2 : (WIN == 2) ? 1 : 0;

    encoder_kernel<<<dim3(32), dim3(256), 0, stream>>>(
        motion, robot, osr, osi, ore, oie,
        Wm, bm, Wr, br, Wre, bre, Wim, bim, Wc, bc, state);
    prep_kernel<<<dim3(257), dim3(256), 0, stream>>>(
        Wk, Wrk, bl, W2k, W2r, blr2, prod_flag, cons_prog);
    fused_kernel<<<dim3(256), dim3(512), 0, stream>>>(
        hist, act, state, W2k, W2r, blr2, Wo, bo,
        zf32, hfing, prod_flag, cons_prog, out, WSH, NW, RS, ring_steps);
}

// Round 3
// 1917.713 us; speedup vs baseline: 1.5208x; 1.5208x over previous
//
#include <hip/hip_runtime.h>
#include <stdint.h>

// ---------------------------------------------------------------------------
// Critic: encoder -> 255-step LSTM (U=256, D_in=256) -> 1-unit relu head. B=512
//
// Round-6 design (fix: __syncthreads() drains vmcnt(0) every step, forcing
// the z-ring prefetch to complete inside each step's critical path):
//  - Recurrence barrier is now lgkmcnt(0)-only (asm + raw s_barrier), so
//    z global loads stay in flight across steps (T4: never drain vmcnt in
//    the main loop). h-exchange only needs LDS visibility.
//  - Window-boundary flag acquire + accA load moved mid-step (covered by
//    half-1 compute), guarded by RS>=2; legacy top-of-step path otherwise.
//  - Weights fully resident (round-1 plan: 6 reg tiles + 2 LDS tiles/wave);
//    NO in-loop streaming (round-5 regression).
//  - hbuf row stride 280 shorts (16B-aligned, ~2-way banks vs ~8-way).
// ---------------------------------------------------------------------------

#define NSTEP 255

typedef __attribute__((ext_vector_type(8))) short short8;   // 8 x bf16
typedef __attribute__((ext_vector_type(4))) float f32x4;

#define HSTR 280   // hbuf row stride in shorts (560 B, 16B-aligned)

__device__ __forceinline__ unsigned short f2bf(float f) {
    union { float f; unsigned int u; } v; v.f = f;
    unsigned int r = v.u + 0x7FFFu + ((v.u >> 16) & 1u);   // RNE
    return (unsigned short)(r >> 16);
}
__device__ __forceinline__ float fexp2(float x) { return __builtin_amdgcn_exp2f(x); }
__device__ __forceinline__ float frcp(float x)  { return __builtin_amdgcn_rcpf(x); }
__device__ __forceinline__ float sigm(float x)  { return frcp(1.0f + fexp2(-1.44269504f * x)); }
__device__ __forceinline__ float tanh_(float x) { return 1.0f - 2.0f * frcp(1.0f + fexp2(2.88539008f * x)); }

// ---------------------------------------------------------------------------
// Encoder: state = relu(concat(ms,rs,re,im) @ Wc + bc)   [512,256] fp32
// ---------------------------------------------------------------------------
__global__ __launch_bounds__(256)
void encoder_kernel(const float* __restrict__ motion, const float* __restrict__ robot,
                    const float* __restrict__ osr, const float* __restrict__ osi,
                    const float* __restrict__ ore, const float* __restrict__ oie,
                    const float* __restrict__ Wm, const float* __restrict__ bm,
                    const float* __restrict__ Wr, const float* __restrict__ br,
                    const float* __restrict__ Wre, const float* __restrict__ bre,
                    const float* __restrict__ Wim, const float* __restrict__ bim,
                    const float* __restrict__ Wc, const float* __restrict__ bc,
                    float* __restrict__ state)
{
    __shared__ float in_m[16][64];
    __shared__ float in_r[16][128];
    __shared__ float in_re[16][128];
    __shared__ float in_im[16][128];
    __shared__ float catb[16 * 768];
    const int t = threadIdx.x;
    const int m0 = blockIdx.x * 16;

    {
        int idx = t * 4; int row = idx >> 6, col = idx & 63;
        *(float4*)&in_m[row][col]       = *(const float4*)(motion + (m0 + row) * 64 + col);
        *(float4*)&in_re[row][col]      = *(const float4*)(osr + (m0 + row) * 64 + col);
        *(float4*)&in_re[row][64 + col] = *(const float4*)(ore + (m0 + row) * 64 + col);
        *(float4*)&in_im[row][col]      = *(const float4*)(osi + (m0 + row) * 64 + col);
        *(float4*)&in_im[row][64 + col] = *(const float4*)(oie + (m0 + row) * 64 + col);
    }
    for (int p = 0; p < 2; ++p) {
        int idx = (t + p * 256) * 4; int row = idx >> 7, col = idx & 127;
        *(float4*)&in_r[row][col] = *(const float4*)(robot + (m0 + row) * 128 + col);
    }
    __syncthreads();

    for (int row = 0; row < 16; ++row) {
        {
            float s = bm[t];
            for (int k = 0; k < 64; ++k) s += in_m[row][k] * Wm[k * 256 + t];
            catb[row * 768 + t] = fmaxf(s, 0.0f);
        }
        {
            float s = br[t];
            for (int k = 0; k < 128; ++k) s += in_r[row][k] * Wr[k * 256 + t];
            catb[row * 768 + 256 + t] = fmaxf(s, 0.0f);
        }
        if (t < 128) {
            float s = bre[t];
            for (int k = 0; k < 128; ++k) s += in_re[row][k] * Wre[k * 128 + t];
            catb[row * 768 + 512 + t] = fmaxf(s, 0.0f);
        } else {
            const int u = t - 128;
            float s = bim[u];
            for (int k = 0; k < 128; ++k) s += in_im[row][k] * Wim[k * 128 + u];
            catb[row * 768 + 640 + u] = fmaxf(s, 0.0f);
        }
    }
    __syncthreads();

    for (int r0 = 0; r0 < 16; r0 += 4) {
        float a0 = bc[t], a1 = bc[t], a2 = bc[t], a3 = bc[t];
        for (int j = 0; j < 768; ++j) {
            const float wv = Wc[j * 256 + t];
            a0 += catb[(r0 + 0) * 768 + j] * wv;
            a1 += catb[(r0 + 1) * 768 + j] * wv;
            a2 += catb[(r0 + 2) * 768 + j] * wv;
            a3 += catb[(r0 + 3) * 768 + j] * wv;
        }
        state[(m0 + r0 + 0) * 256 + t] = fmaxf(a0, 0.0f);
        state[(m0 + r0 + 1) * 256 + t] = fmaxf(a1, 0.0f);
        state[(m0 + r0 + 2) * 256 + t] = fmaxf(a2, 0.0f);
        state[(m0 + r0 + 3) * 256 + t] = fmaxf(a3, 0.0f);
    }
}

// ---------------------------------------------------------------------------
// Prep: W2k/W2r in frag-linear layout [(T*8+kk)*64+lane][8], bf16.
//   Tile T = wv4*16 + gam*4 + g  -> orig col = g*256 + wv4*64 + gam*16 + cid
//   frag element j: k = kk*32 + (lane>>4)*8 + j  (B layout: n=lane&15).
// blr2[T*64+lane] = bl[orig col].  Also zero flags.
// ---------------------------------------------------------------------------
__global__ __launch_bounds__(256)
void prep_kernel(const float* __restrict__ Wk, const float* __restrict__ Wrk,
                 const float* __restrict__ bl,
                 unsigned short* __restrict__ W2k, unsigned short* __restrict__ W2r,
                 float* __restrict__ blr2,
                 unsigned int* __restrict__ prod_flag, unsigned int* __restrict__ cons_prog)
{
    const int blk = blockIdx.x, t = threadIdx.x;
    if (blk < 256) {
        const int mat = blk >> 7;
        const int idx = (blk & 127) * 256 + t;      // (T*8+kk)*64+lane
        const int T = idx >> 9, kk = (idx >> 6) & 7, lane = idx & 63;
        const int q = lane >> 4, cid = lane & 15;
        const int wv = T >> 4, gam = (T >> 2) & 3, g = T & 3;
        const int col = g * 256 + wv * 64 + gam * 16 + cid;
        const float* W = mat ? Wrk : Wk;
        unsigned short* O = mat ? W2r : W2k;
#pragma unroll
        for (int j = 0; j < 8; ++j) {
            const int k = kk * 32 + q * 8 + j;
            O[(size_t)idx * 8 + j] = f2bf(W[(size_t)k * 1024 + col]);
        }
    } else {
        for (int e = t; e < 4096; e += 256) {
            const int T = e >> 6, lane = e & 63, cid = lane & 15;
            const int wv = T >> 4, gam = (T >> 2) & 3, g = T & 3;
            blr2[e] = bl[g * 256 + wv * 64 + gam * 16 + cid];
        }
        for (int i = t; i < 40960; i += 256) prod_flag[i] = 0u;
        for (int i = t; i < 512; i += 256) cons_prog[i] = 0u;
    }
}

// ---------------------------------------------------------------------------
// Fused: blocks 0..31 = consumers (recurrence, 8 waves), 32..255 = producers.
// z ring is f32 C-fragments: z[(slot*32+m)*16384 + (T*64+lane)*4 .. +3]
// ---------------------------------------------------------------------------
__global__ __launch_bounds__(512, 2)
void fused_kernel(const float* __restrict__ hist, const float* __restrict__ act,
                  const float* __restrict__ state,
                  const unsigned short* __restrict__ W2k, const unsigned short* __restrict__ W2r,
                  const float* __restrict__ blr2,
                  const float* __restrict__ Wo, const float* __restrict__ bo_p,
                  float* __restrict__ zf32, float* __restrict__ hfing,
                  unsigned int* __restrict__ prod_flag, unsigned int* __restrict__ cons_prog,
                  float* __restrict__ out,
                  int WSH, int NW, int RS, int ring_steps)
{
    __shared__ __align__(16) unsigned char smem[148992];
    unsigned short* ldsW = (unsigned short*)smem;                 // 131072 B (2 Wrk tiles / wave)
    unsigned short* hbuf0 = (unsigned short*)(smem + 131072);     // 16*HSTR*2 = 8960 B
    unsigned short* hbuf1 = (unsigned short*)(smem + 140032);     // 8960 B

    const int tid = threadIdx.x;
    const int w = tid >> 6, lane = tid & 63, q = lane >> 4, cid = lane & 15;
    const int bx = blockIdx.x;
    const int WIN = 1 << WSH, WMASK = WIN - 1;

    if (bx < 32) {
        // ======================= CONSUMER =======================
        const int m = bx, m0 = m * 16;
        // wave w owns tiles T = w*8 + h*4 + g  (h=half, g=gate i/f/g/o)
        const int u0 = (w >> 1) * 64 + ((w & 1) * 2 + 0) * 16 + cid;
        const int u1 = u0 + 16;

        // register-resident Wrk: tiles j=0..5 (192 regs, mostly AGPR)
        short8 Wres[6][8];
#pragma unroll
        for (int t = 0; t < 6; ++t) {
#pragma unroll
            for (int kk = 0; kk < 8; ++kk)
                Wres[t][kk] = *(const short8*)(W2r + ((size_t)((w * 8 + t) * 8 + kk) * 64 + lane) * 8);
        }
        // LDS-resident Wrk: tiles j=6,7
#pragma unroll
        for (int tt = 0; tt < 2; ++tt) {
#pragma unroll
            for (int kk = 0; kk < 8; ++kk) {
                short8 f = *(const short8*)(W2r + ((size_t)((w * 8 + 6 + tt) * 8 + kk) * 64 + lane) * 8);
                *(short8*)(ldsW + (((w * 2 + tt) * 8 + kk) * 64 + lane) * 8) = f;
            }
        }
        // h^0 = bf16(state tile): 512 threads x 8 elems
        {
            const int row = tid >> 5, c0 = (tid & 31) * 8;
            const float* sp = state + (size_t)(m0 + row) * 256 + c0;
            const float4 a = *(const float4*)sp;
            const float4 b = *(const float4*)(sp + 4);
            union { unsigned short us[8]; short8 v; } pk;
            pk.us[0] = f2bf(a.x); pk.us[1] = f2bf(a.y); pk.us[2] = f2bf(a.z); pk.us[3] = f2bf(a.w);
            pk.us[4] = f2bf(b.x); pk.us[5] = f2bf(b.y); pk.us[6] = f2bf(b.z); pk.us[7] = f2bf(b.w);
            *(short8*)(hbuf0 + row * HSTR + c0) = pk.v;
        }
        // c^0
        float cc[8];
#pragma unroll
        for (int h = 0; h < 2; ++h)
#pragma unroll
            for (int r = 0; r < 4; ++r)
                cc[h * 4 + r] = state[(size_t)(m0 + q * 4 + r) * 256 + (h ? u1 : u0)];

        __syncthreads();

        unsigned short* hcur = hbuf0;
        unsigned short* hnxt = hbuf1;
        int zslot = 0;
        f32x4 accA[4], accB[4];
        const float* zbw = zf32 + (size_t)lane * 4 + (size_t)w * 2048;  // + w*8*256

        // prologue: window 0 acquire + accA(s=0)
        while (__hip_atomic_load(&prod_flag[m * 4],
                                 __ATOMIC_ACQUIRE, __HIP_MEMORY_SCOPE_AGENT) == 0)
            __builtin_amdgcn_s_sleep(1);
        {
            const float* zb0 = zbw + (size_t)m * 16384;
#pragma unroll
            for (int g = 0; g < 4; ++g)
                accA[g] = *(const f32x4*)(zb0 + g * 256);
        }

        for (int s = 0; s < NSTEP; ++s) {
            const bool last = (s == NSTEP - 1);

            // legacy path (RS<2): boundary acquire at step top
            if (RS < 2 && (s & WMASK) == 0 && s > 0) {
                const int f = s >> WSH;
                while (__hip_atomic_load(&prod_flag[(f * 32 + m) * 4],
                                         __ATOMIC_ACQUIRE, __HIP_MEMORY_SCOPE_AGENT) == 0)
                    __builtin_amdgcn_s_sleep(1);
                const float* zb0 = zbw + ((size_t)zslot * 32 + m) * 16384;
#pragma unroll
                for (int g = 0; g < 4; ++g)
                    accA[g] = *(const f32x4*)(zb0 + g * 256);
            }
            // accB: half-1 z of current step (covered by half-0 compute)
            {
                const float* zb1 = zbw + ((size_t)zslot * 32 + m) * 16384 + 1024;
#pragma unroll
                for (int g = 0; g < 4; ++g)
                    accB[g] = *(const f32x4*)(zb1 + g * 256);
            }
            const unsigned short* hrow = hcur + cid * HSTR + q * 8;

            // half 0: tiles 0..3, all register-resident
            __builtin_amdgcn_s_setprio(1);
#pragma unroll
            for (int kk = 0; kk < 8; ++kk) {
                const short8 a = *(const short8*)(hrow + kk * 32);
                accA[0] = __builtin_amdgcn_mfma_f32_16x16x32_bf16(a, Wres[0][kk], accA[0], 0, 0, 0);
                accA[1] = __builtin_amdgcn_mfma_f32_16x16x32_bf16(a, Wres[1][kk], accA[1], 0, 0, 0);
                accA[2] = __builtin_amdgcn_mfma_f32_16x16x32_bf16(a, Wres[2][kk], accA[2], 0, 0, 0);
                accA[3] = __builtin_amdgcn_mfma_f32_16x16x32_bf16(a, Wres[3][kk], accA[3], 0, 0, 0);
            }
            __builtin_amdgcn_s_setprio(0);

#pragma unroll
            for (int r = 0; r < 4; ++r) {
                const float c = sigm(accA[1][r]) * cc[r] + sigm(accA[0][r]) * tanh_(accA[2][r]);
                cc[r] = c;
                const float hv = sigm(accA[3][r]) * tanh_(c);
                if (!last) hnxt[(q * 4 + r) * HSTR + u0] = f2bf(hv);
                else       hfing[(size_t)(m0 + q * 4 + r) * 256 + u0] = hv;
            }

            // prefetch z(s+1) half-0 into accA; at window boundary, acquire
            // the next window's flag first (covered by half-1 compute).
            const int znext = (zslot + 1 == ring_steps) ? 0 : zslot + 1;
            if (!last && RS >= 2) {
                if (((s + 1) & WMASK) == 0) {
                    const int fn = (s + 1) >> WSH;
                    while (__hip_atomic_load(&prod_flag[(fn * 32 + m) * 4],
                                             __ATOMIC_ACQUIRE, __HIP_MEMORY_SCOPE_AGENT) == 0)
                        __builtin_amdgcn_s_sleep(1);
                }
                const float* zbn = zbw + ((size_t)znext * 32 + m) * 16384;
#pragma unroll
                for (int g = 0; g < 4; ++g)
                    accA[g] = *(const f32x4*)(zbn + g * 256);
            } else if (!last && (((s + 1) & WMASK) != 0)) {
                const float* zbn = zbw + ((size_t)znext * 32 + m) * 16384;
#pragma unroll
                for (int g = 0; g < 4; ++g)
                    accA[g] = *(const f32x4*)(zbn + g * 256);
            }

            // half 1: tiles 4,5 resident + 6,7 LDS
            __builtin_amdgcn_s_setprio(1);
#pragma unroll
            for (int kk = 0; kk < 8; ++kk) {
                const short8 a = *(const short8*)(hrow + kk * 32);
                accB[0] = __builtin_amdgcn_mfma_f32_16x16x32_bf16(a, Wres[4][kk], accB[0], 0, 0, 0);
                accB[1] = __builtin_amdgcn_mfma_f32_16x16x32_bf16(a, Wres[5][kk], accB[1], 0, 0, 0);
                const short8 b6 = *(const short8*)(ldsW + (((w * 2 + 0) * 8 + kk) * 64 + lane) * 8);
                accB[2] = __builtin_amdgcn_mfma_f32_16x16x32_bf16(a, b6, accB[2], 0, 0, 0);
                const short8 b7 = *(const short8*)(ldsW + (((w * 2 + 1) * 8 + kk) * 64 + lane) * 8);
                accB[3] = __builtin_amdgcn_mfma_f32_16x16x32_bf16(a, b7, accB[3], 0, 0, 0);
            }
            __builtin_amdgcn_s_setprio(0);

#pragma unroll
            for (int r = 0; r < 4; ++r) {
                const float c = sigm(accB[1][r]) * cc[4 + r] + sigm(accB[0][r]) * tanh_(accB[2][r]);
                cc[4 + r] = c;
                const float hv = sigm(accB[3][r]) * tanh_(c);
                if (!last) hnxt[(q * 4 + r) * HSTR + u1] = f2bf(hv);
                else       hfing[(size_t)(m0 + q * 4 + r) * 256 + u1] = hv;
            }

            // lgkm-only barrier: h-exchange needs LDS visibility ONLY.
            // z prefetch (vmcnt) stays in flight across steps.
            asm volatile("s_waitcnt lgkmcnt(0)" ::: "memory");
            __builtin_amdgcn_s_barrier();

            { unsigned short* t_ = hcur; hcur = hnxt; hnxt = t_; }
            if (((s + 1) & WMASK) == 0 && tid == 0)
                __hip_atomic_store(&cons_prog[m * 16], (unsigned)((s + 1) >> WSH),
                                   __ATOMIC_RELEASE, __HIP_MEMORY_SCOPE_AGENT);
            zslot = znext;
        }

        __syncthreads();   // full drain before head (hfing global stores)

        // head: out = relu(h_final @ Wo + bo)
        float* redL = (float*)smem;       // reuse ldsW region
        if (tid < 256) {
            const int row = tid >> 4, c16 = tid & 15;
            float part = 0.0f;
#pragma unroll
            for (int j = 0; j < 16; ++j) {
                const int u = c16 + j * 16;
                part += hfing[(size_t)(m0 + row) * 256 + u] * Wo[u];
            }
            redL[row * 16 + c16] = part;
        }
        __syncthreads();
        if (tid < 16) {
            float sum = 0.0f;
#pragma unroll
            for (int j = 0; j < 16; ++j) sum += redL[tid * 16 + j];
            out[m0 + tid] = fmaxf(sum + bo_p[0], 0.0f);
        }
    } else {
        // ======================= PRODUCER =======================
        const int p = bx - 32;
        const int total = NW * 32;
        const int slot0 = w & 3, tchalf = w >> 2;   // 4 step-slots x 2 Tc halves
        for (int tau = p; tau < total; tau += 224) {
            const int w_ = tau >> 5, m = tau & 31, m0 = m * 16;
            const int nst = (WIN < NSTEP - w_ * WIN) ? WIN : (NSTEP - w_ * WIN);
            if (w_ >= RS) {
                const unsigned need = (unsigned)(w_ - RS + 1);
                while (__hip_atomic_load(&cons_prog[m * 16],
                                         __ATOMIC_ACQUIRE, __HIP_MEMORY_SCOPE_AGENT) < need)
                    __builtin_amdgcn_s_sleep(4);
            }
            int ns_my = 0; int sabs[2] = {0, 0};
            for (int sl = slot0; sl < nst; sl += 4) { if (ns_my < 2) sabs[ns_my++] = w_ * WIN + sl; }

            short8 A2[2][8];
#pragma unroll
            for (int si = 0; si < 2; ++si) {
                if (si < ns_my) {
                    const int s = sabs[si];
                    const float* xs = (s < 127)
                        ? hist + ((size_t)(m0 + cid) * 128 + s) * 256
                        : act + ((size_t)(m0 + cid) * 128 + (s - 127)) * 256;
#pragma unroll
                    for (int kk = 0; kk < 8; ++kk) {
                        const float4 a = *(const float4*)(xs + kk * 32 + q * 8);
                        const float4 b = *(const float4*)(xs + kk * 32 + q * 8 + 4);
                        union { unsigned short us[8]; short8 v; } pk;
                        pk.us[0] = f2bf(a.x); pk.us[1] = f2bf(a.y);
                        pk.us[2] = f2bf(a.z); pk.us[3] = f2bf(a.w);
                        pk.us[4] = f2bf(b.x); pk.us[5] = f2bf(b.y);
                        pk.us[6] = f2bf(b.z); pk.us[7] = f2bf(b.w);
                        A2[si][kk] = pk.v;
                    }
                }
            }
            if (ns_my > 0) {
                for (int Tc = tchalf * 8; Tc < tchalf * 8 + 8; ++Tc) {
                    float bias[4];
#pragma unroll
                    for (int t = 0; t < 4; ++t) bias[t] = blr2[(Tc * 4 + t) * 64 + lane];
                    f32x4 acc[2][4];
#pragma unroll
                    for (int si = 0; si < 2; ++si)
#pragma unroll
                        for (int t = 0; t < 4; ++t)
                            acc[si][t] = (f32x4){bias[t], bias[t], bias[t], bias[t]};
#pragma unroll
                    for (int kk = 0; kk < 8; ++kk) {
                        short8 Wf[4];
#pragma unroll
                        for (int t = 0; t < 4; ++t)
                            Wf[t] = *(const short8*)(W2k + ((size_t)((Tc * 4 + t) * 8 + kk) * 64 + lane) * 8);
#pragma unroll
                        for (int t = 0; t < 4; ++t) {
                            acc[0][t] = __builtin_amdgcn_mfma_f32_16x16x32_bf16(A2[0][kk], Wf[t], acc[0][t], 0, 0, 0);
                            if (ns_my > 1)
                                acc[1][t] = __builtin_amdgcn_mfma_f32_16x16x32_bf16(A2[1][kk], Wf[t], acc[1][t], 0, 0, 0);
                        }
                    }
#pragma unroll
                    for (int si = 0; si < 2; ++si) {
                        if (si < ns_my) {
                            const int zsl = sabs[si] % ring_steps;
                            float* zo_ = zf32 + ((size_t)zsl * 32 + m) * 16384 + (size_t)lane * 4;
#pragma unroll
                            for (int t = 0; t < 4; ++t)
                                *(f32x4*)(zo_ + (Tc * 4 + t) * 256) = acc[si][t];
                        }
                    }
                }
            }
            __syncthreads();   // full drain: all waves' z stores before flag
            if (tid == 0)
                __hip_atomic_store(&prod_flag[(w_ * 32 + m) * 4], 1u,
                                   __ATOMIC_RELEASE, __HIP_MEMORY_SCOPE_AGENT);
        }
    }
}

// ---------------------------------------------------------------------------
extern "C" void kernel_launch(void* const* d_in, const int* in_sizes, int n_in,
                              void* d_out, int out_size, void* d_ws, size_t ws_size,
                              hipStream_t stream)
{
    const float* motion = (const float*)d_in[0];
    const float* robot  = (const float*)d_in[1];
    const float* osr    = (const float*)d_in[2];
    const float* osi    = (const float*)d_in[3];
    const float* hist   = (const float*)d_in[4];
    const float* act    = (const float*)d_in[5];
    const float* ore    = (const float*)d_in[6];
    const float* oie    = (const float*)d_in[7];
    const float* Wm  = (const float*)d_in[8];  const float* bm  = (const float*)d_in[9];
    const float* Wr  = (const float*)d_in[10]; const float* br  = (const float*)d_in[11];
    const float* Wre = (const float*)d_in[12]; const float* bre = (const float*)d_in[13];
    const float* Wim = (const float*)d_in[14]; const float* bim = (const float*)d_in[15];
    const float* Wc  = (const float*)d_in[16]; const float* bc  = (const float*)d_in[17];
    const float* Wk  = (const float*)d_in[18];
    const float* Wrk = (const float*)d_in[19];
    const float* bl  = (const float*)d_in[20];
    const float* Wo  = (const float*)d_in[21]; const float* bo  = (const float*)d_in[22];

    char* ws = (char*)d_ws;
    float*          state     = (float*)(ws + 0);                  // 524288
    unsigned short* W2k       = (unsigned short*)(ws + 524288);    // 524288
    unsigned short* W2r       = (unsigned short*)(ws + 1048576);   // 524288
    float*          blr2      = (float*)(ws + 1572864);            // 16384
    unsigned int*   prod_flag = (unsigned int*)(ws + 1589248);     // 163840
    unsigned int*   cons_prog = (unsigned int*)(ws + 1753088);     // 2048
    float*          hfing     = (float*)(ws + 1755136);            // 524288 final-h scratch
    float*          zf32      = (float*)(ws + 2279424);            // f32 ring
    float*          out       = (float*)d_out;

    // adaptive ring: per-step z is 2 MB (32 tiles x 64 KB f32)
    size_t avail = (ws_size > 2279424) ? ws_size - 2279424 : 0;
    long rs_max = (long)(avail / 2097152);
    int WIN = 1, NW = 255, RS = 1;
    const int wins[4] = {8, 4, 2, 1};
    for (int i = 0; i < 4; ++i) {
        const int Wn = wins[i];
        const int nw = (NSTEP + Wn - 1) / Wn;
        long rs = rs_max / Wn; if (rs > nw) rs = nw;
        if (rs >= 2) { WIN = Wn; NW = nw; RS = (int)rs; break; }
        if (Wn == 1) { WIN = 1; NW = nw; RS = (int)(rs >= 1 ? rs : 1); }
    }
    int ring_steps = RS * WIN; if (ring_steps < 1) ring_steps = 1;
    const int WSH = (WIN == 8) ? 3 : (WIN == 4) ? 2 : (WIN == 2) ? 1 : 0;

    encoder_kernel<<<dim3(32), dim3(256), 0, stream>>>(
        motion, robot, osr, osi, ore, oie,
        Wm, bm, Wr, br, Wre, bre, Wim, bim, Wc, bc, state);
    prep_kernel<<<dim3(257), dim3(256), 0, stream>>>(
        Wk, Wrk, bl, W2k, W2r, blr2, prod_flag, cons_prog);
    fused_kernel<<<dim3(256), dim3(512), 0, stream>>>(
        hist, act, state, W2k, W2r, blr2, Wo, bo,
        zf32, hfing, prod_flag, cons_prog, out, WSH, NW, RS, ring_steps);
}